// Round 5
// baseline (4680.888 us; speedup 1.0000x reference)
//
#include <hip/hip_runtime.h>
#include <hip/hip_bf16.h>
#include <hip/hip_fp16.h>

// LSTM_RNN: B=128, T=512, E=256, U=512. R5: incremental stripe consumption.
//   - 128 wgs = 4 batch-quarters x 32 unit-slices (16 units / 64 gate cols).
//   - H exchange: blocked tagged layout HBuf u32[2][4][32 slices][32 rows][16
//     units], value = (tag<<16)|fp16. Producer (q,s) writes one contiguous
//     2KB block per step. Consumer waves poll their 16 assigned blocks
//     INDEPENDENTLY and fire that stripe's 2 MFMAs the moment it's fresh --
//     A-frag comes straight from the 2 loaded u64s (no LDS slab, no B2).
//     Producer skew overlaps with compute instead of summing into the step.
//   - x-GEMM split across all 8 waves (48 MFMA/wave balanced); reduce scratch
//     double-buffered by step parity -> ONE barrier per step.
//   - Safety: per-value tag gating (t+1 parity induction as R4); poisoned
//     0xAAAA tags never match t in [0,512]. 128 wgs < 256 CUs -> co-resident.
// ws layout (~34.1 MiB):
//   X    fp16 [T][B][E]           @ 0          (33,554,432 B)
//   HBuf u32  [2][4][32][32][16]  @ 33,554,432 (524,288 B)

#define B_ 128
#define T_ 512
#define E_ 256
#define U_ 512
#define NWG_ 128
#define KP_ 772     // weight row stride (halves)

typedef __attribute__((ext_vector_type(4))) _Float16 half4;
typedef __attribute__((ext_vector_type(4))) float floatx4;
typedef __attribute__((ext_vector_type(2))) unsigned int uint2v;
typedef unsigned long long u64t;
typedef unsigned int u32t;

__device__ __forceinline__ float sigmf(float x) { return 1.0f / (1.0f + __expf(-x)); }
__device__ __forceinline__ float tanh_f(float x) { return 2.0f / (1.0f + __expf(-2.0f * x)) - 1.0f; }

__global__ void init_ws_kernel(u32t* __restrict__ hbuf) {
  int gid = blockIdx.x * blockDim.x + threadIdx.x;
  int n = blockDim.x * gridDim.x;
  // parity-0 blocks: tag 0, h = 0  (h_0). parity-1 stays poisoned (0xAAAA != t).
  for (int i = gid; i < 4 * 32 * 32 * 16; i += n) hbuf[i] = 0u;
}

// X[t][b][e] = (fp16) emb[sentence[b][t]][e]; one thread = 8 elements.
__global__ void prep_x_kernel(const int* __restrict__ sent,
                              const float* __restrict__ emb,
                              _Float16* __restrict__ X) {
  int gid = blockIdx.x * blockDim.x + threadIdx.x;  // 2,097,152 total
  int e8 = gid & 31;
  int row = gid >> 5;         // row = t*128 + b
  int b = row & 127;
  int t = row >> 7;
  int word = sent[b * T_ + t];
  const float* src = emb + (size_t)word * E_ + e8 * 8;
  float4 v0 = *(const float4*)(src);
  float4 v1 = *(const float4*)(src + 4);
  half4 o0 = {(_Float16)v0.x, (_Float16)v0.y, (_Float16)v0.z, (_Float16)v0.w};
  half4 o1 = {(_Float16)v1.x, (_Float16)v1.y, (_Float16)v1.z, (_Float16)v1.w};
  _Float16* dst = X + (size_t)row * E_ + e8 * 8;
  *(half4*)dst = o0;
  *(half4*)(dst + 4) = o1;
}

__global__ __launch_bounds__(512, 1) void lstm_kernel(
    const _Float16* __restrict__ X,
    const float* __restrict__ Wx, const float* __restrict__ Wh,
    const float* __restrict__ bias,
    u32t* __restrict__ HBuf) {
  // LDS: Wl [64][KP_] fp16 (98,816 B) | Rs float[2][8][256] (16,384 B)
  //    = 115,200 B. 1 wg/CU.
  __shared__ __align__(16) char smem[115200];
  _Float16* Wl = (_Float16*)smem;
  float* Rs = (float*)(smem + 98816);

  const int g = blockIdx.x;
  const int q = g >> 5;   // batch quarter: rows q*32 .. q*32+31
  const int s = g & 31;   // unit slice: units s*16 .. s*16+15
  const int tid = threadIdx.x;
  const int lane = tid & 63;
  const int wave = tid >> 6;      // 8 waves
  const int p16 = lane & 15;
  const int quad = lane >> 4;
  const int sg = wave & 1;        // unit subgroup (8 units)
  const int mt = (wave >> 1) & 1; // M-tile (16 batch rows)
  const int kh = wave >> 2;       // 0: x[0,128)+h[256,512)+epilogue; 1: x[128,256)+h[0,256)

  // ---- one-time: stage weight slice [768 x 64] into LDS ----
  for (int idx = tid; idx < 64 * 768; idx += 512) {
    int c = idx & 63, k = idx >> 6;
    int cc = c & 31;
    int gi = ((cc >> 3) & 1) + ((cc >> 4) << 1);       // 0=i,1=f,2=g,3=o
    int C = gi * 512 + s * 16 + (c >> 5) * 8 + (cc & 7);
    float w = (k < E_) ? Wx[(size_t)k * 2048 + C] : Wh[(size_t)(k - E_) * 2048 + C];
    Wl[c * KP_ + k] = (_Float16)w;
  }
  __syncthreads();

  const bool lo = (p16 < 8);
  const int uo = p16 & 7;
  const int gu = s * 16 + sg * 8 + uo;               // global unit id
  const float bias0 = bias[(lo ? 0 : 512) + gu];     // i or f
  const float bias1 = bias[(lo ? 1024 : 1536) + gu]; // g or o

  float cst[4] = {0.f, 0.f, 0.f, 0.f};  // c-state (kh0 lo lanes)

  const int brow = q * 32 + mt * 16 + p16;  // A-frag batch row
  const int ko = quad * 4;

  const _Float16* bp0 = &Wl[(sg * 32 + p16) * KP_ + ko];       // [i|f] col
  const _Float16* bp1 = &Wl[(sg * 32 + 16 + p16) * KP_ + ko];  // [g|o] col

  // consumer: lane's offset inside a 2KB block [32 rows][16 u32]
  const int loff = (mt * 16 + p16) * 16 + quad * 4;
  const int sb = kh ? 0 : 16;   // my 16 stripes: kh0 -> sigma 16..31, kh1 -> 0..15
  const u64t TM = 0xffff0000ffff0000ULL;

  for (int t = 0; t < T_; ++t) {
    const int pin = t & 1, pout = (t + 1) & 1;

    floatx4 acc0 = {0.f, 0.f, 0.f, 0.f};
    floatx4 acc1 = {0.f, 0.f, 0.f, 0.f};

    // ---- x-part (no h dependency): kh0 k in [0,128), kh1 k in [128,256) ----
    const _Float16* xr = X + ((size_t)t * B_ + brow) * E_ + ko;
#pragma unroll
    for (int kk = 0; kk < 8; ++kk) {
      int k = kh * 8 + kk;
      half4 a = *(const half4*)(xr + k * 16);
      half4 b0v = *(const half4*)(bp0 + k * 16);
      half4 b1v = *(const half4*)(bp1 + k * 16);
      acc0 = __builtin_amdgcn_mfma_f32_16x16x16f16(a, b0v, acc0, 0, 0, 0);
      acc1 = __builtin_amdgcn_mfma_f32_16x16x16f16(a, b1v, acc1, 0, 0, 0);
    }

    // ---- h stripes: poll own 16 blocks, MFMA each the moment it's fresh ----
    const u32t* qbase = HBuf + ((size_t)pin * 4 + q) * (32 * 512);
    const u64t tp = ((u64t)(u32t)t << 48) | ((u64t)(u32t)t << 16);
    u64t va[16], vb[16];
    unsigned rem = 0xffffu;
    for (;;) {
      unsigned pend = rem;
#pragma unroll
      for (int j = 0; j < 16; ++j) {
        if ((pend >> j) & 1u) {
          const u64t* src =
              (const u64t*)(qbase + (size_t)(sb + j) * 512 + loff);
          va[j] = __hip_atomic_load(src, __ATOMIC_RELAXED,
                                    __HIP_MEMORY_SCOPE_AGENT);
          vb[j] = __hip_atomic_load(src + 1, __ATOMIC_RELAXED,
                                    __HIP_MEMORY_SCOPE_AGENT);
        }
      }
#pragma unroll
      for (int j = 0; j < 16; ++j) {
        if ((pend >> j) & 1u) {
          bool fresh = (((va[j] ^ tp) & TM) == 0) & (((vb[j] ^ tp) & TM) == 0);
          if (__all(fresh)) {
            u32t l0 = ((u32t)va[j] & 0xffffu) | ((u32t)(va[j] >> 32) << 16);
            u32t l1 = ((u32t)vb[j] & 0xffffu) | ((u32t)(vb[j] >> 32) << 16);
            uint2v pk = {l0, l1};
            half4 a = __builtin_bit_cast(half4, pk);
            int hk = sb + j;
            half4 b0v = *(const half4*)(bp0 + 256 + hk * 16);
            half4 b1v = *(const half4*)(bp1 + 256 + hk * 16);
            acc0 = __builtin_amdgcn_mfma_f32_16x16x16f16(a, b0v, acc0, 0, 0, 0);
            acc1 = __builtin_amdgcn_mfma_f32_16x16x16f16(a, b1v, acc1, 0, 0, 0);
            rem &= ~(1u << j);
          }
        }
      }
      if (!rem) break;  // wave-uniform
      __builtin_amdgcn_s_sleep(1);
    }

    // ---- kh1 partials -> Rs[parity] ----
    if (kh == 1) {
      int base = (wave - 4) * 64 + lane;
      float* Rp = Rs + pin * 2048;
#pragma unroll
      for (int r = 0; r < 4; ++r) {
        Rp[r * 256 + base] = acc0[r];
        Rp[(4 + r) * 256 + base] = acc1[r];
      }
    }
    __syncthreads();  // B3: the ONLY per-step barrier (Rs parity handles WAR)

    // ---- epilogue (kh0): gates, c/h update, tagged block publish ----
    if (kh == 0) {
      int base = wave * 64 + lane;
      const float* Rp = Rs + pin * 2048;
      u32t* blk = HBuf + ((size_t)pout * 4 + q) * (32 * 512) + (size_t)s * 512;
#pragma unroll
      for (int r = 0; r < 4; ++r) {
        float z0 = acc0[r] + Rp[r * 256 + base] + bias0;       // i (lo)/ f (hi)
        float z1 = acc1[r] + Rp[(4 + r) * 256 + base] + bias1; // g (lo)/ o (hi)
        float s0 = sigmf(z0);
        float s1 = lo ? tanh_f(z1) : sigmf(z1);
        float prod = s0 * s1;                          // i*g on lo lanes
        float fg = __shfl_xor(lo ? prod : s0, 8, 64);  // lo receives f
        float og = __shfl_xor(s1, 8, 64);              // lo receives o
        if (lo) {
          float cn = fg * cst[r] + prod;
          cst[r] = cn;
          float h = og * tanh_f(cn);
          int rowl = mt * 16 + quad * 4 + r;           // local row in quarter
          _Float16 hf16 = (_Float16)h;
          u32t hb = ((u32t)(t + 1) << 16) |
                    (u32t)__builtin_bit_cast(unsigned short, hf16);
          __hip_atomic_store(&blk[rowl * 16 + sg * 8 + uo], hb,
                             __ATOMIC_RELAXED, __HIP_MEMORY_SCOPE_AGENT);
        }
      }
    }
    // no end barrier: consumers gate on per-value tags.
  }
}

// MLP head: one block per batch row. h(512)->relu 128->relu 64->sigmoid 1.
// h_T lives in HBuf parity 0 (T=512 even), tag 512, blocked layout.
__global__ void head_kernel(const u32t* __restrict__ HBuf,
                            const float* __restrict__ W1, const float* __restrict__ b1,
                            const float* __restrict__ W2, const float* __restrict__ b2,
                            const float* __restrict__ W3, const float* __restrict__ b3,
                            float* __restrict__ out) {
  __shared__ float hs[512];
  __shared__ float h1[128];
  __shared__ float h2[64];
  int row = blockIdx.x;
  int tid = threadIdx.x;  // 128 threads
  int q = row >> 5, r = row & 31;
  for (int k = tid; k < 512; k += 128) {
    int sig = k >> 4, u = k & 15;
    u32t v = HBuf[((size_t)q * 32 + sig) * 512 + r * 16 + u];
    unsigned short hb16 = (unsigned short)(v & 0xffffu);
    hs[k] = (float)__builtin_bit_cast(_Float16, hb16);
  }
  __syncthreads();
  float a = b1[tid];
  for (int k = 0; k < 512; ++k) a += hs[k] * W1[k * 128 + tid];
  h1[tid] = fmaxf(a, 0.0f);
  __syncthreads();
  if (tid < 64) {
    float a2 = b2[tid];
    for (int k = 0; k < 128; ++k) a2 += h1[k] * W2[k * 64 + tid];
    h2[tid] = fmaxf(a2, 0.0f);
  }
  __syncthreads();
  if (tid == 0) {
    float a3 = b3[0];
    for (int k = 0; k < 64; ++k) a3 += h2[k] * W3[k];
    out[row] = 1.0f / (1.0f + __expf(-a3));
  }
}

extern "C" void kernel_launch(void* const* d_in, const int* in_sizes, int n_in,
                              void* d_out, int out_size, void* d_ws, size_t ws_size,
                              hipStream_t stream) {
  const int* sent = (const int*)d_in[0];
  const float* emb = (const float*)d_in[1];
  const float* Wx = (const float*)d_in[2];
  const float* Wh = (const float*)d_in[3];
  const float* b = (const float*)d_in[4];
  const float* W1 = (const float*)d_in[5];
  const float* b1 = (const float*)d_in[6];
  const float* W2 = (const float*)d_in[7];
  const float* b2 = (const float*)d_in[8];
  const float* W3 = (const float*)d_in[9];
  const float* b3 = (const float*)d_in[10];
  float* out = (float*)d_out;

  char* ws = (char*)d_ws;
  _Float16* X = (_Float16*)(ws);
  u32t* HBuf = (u32t*)(ws + (size_t)33554432);

  init_ws_kernel<<<64, 256, 0, stream>>>(HBuf);
  prep_x_kernel<<<8192, 256, 0, stream>>>(sent, emb, X);
  lstm_kernel<<<NWG_, 512, 0, stream>>>(X, Wx, Wh, b, HBuf);
  head_kernel<<<128, 128, 0, stream>>>(HBuf, W1, b1, W2, b2, W3, b3, out);
}

// Round 6
// 3286.831 us; speedup vs baseline: 1.4241x; 1.4241x over previous
//
#include <hip/hip_runtime.h>
#include <hip/hip_bf16.h>
#include <hip/hip_fp16.h>

// LSTM_RNN: B=128, T=512, E=256, U=512. R6: R4 skeleton + register-resident
// weights + K=32 MFMA + 4-way K-split.
//   - 128 wgs = 4 batch-quarters x 32 unit-slices (16 units / 64 gate cols).
//   - Handshake: R4's proven tag-in-data (u32 = tag<<16 | fp16), coalesced
//     u64 chunk staging with retry-until-fresh, LDS slab, 2 barriers/step.
//     (R5's per-stripe uncoalesced polling regressed 1.7x -- reverted.)
//   - NEW: B-fragments (weights) gathered ONCE into VGPRs (12 x half8/wave),
//     Wl LDS array deleted -> ~196KB/step of LDS reads gone.
//   - NEW: mfma_f32_16x16x32_f16 (gfx950): half the MFMA count, A-frag =
//     one ds_read_b128 (slab row stride 1040B = 65*16B: 2-way phase, free).
//   - NEW: 8 waves = 4 K-quarters (kq, 6 K32-blocks each) x 2 unit-subgroups;
//     partial sums reduced through floatx4 LDS slots; waves 0-3 do epilogue.
//   - LDS: slab 33,280 B + Rs 65,536 B = 98,816 B. 1 wg/CU, co-resident.
// ws layout (~34.1 MiB):
//   X   fp16 [T][B][E]   @ 0          (33,554,432 B)
//   H0  u32  [B][U]      @ 33,554,432 (262,144 B)
//   H1  u32  [B][U]      @ 33,816,576 (262,144 B)

#define B_ 128
#define T_ 512
#define E_ 256
#define U_ 512
#define NWG_ 128
#define HROW_ 520   // H-slab row stride (halves); 1040B = 65*16B

typedef __attribute__((ext_vector_type(8))) _Float16 half8;
typedef __attribute__((ext_vector_type(4))) float floatx4;
typedef unsigned long long u64t;
typedef unsigned int u32t;

__device__ __forceinline__ float sigmf(float x) { return 1.0f / (1.0f + __expf(-x)); }
__device__ __forceinline__ float tanh_f(float x) { return 2.0f / (1.0f + __expf(-2.0f * x)) - 1.0f; }

__global__ void init_ws_kernel(u32t* __restrict__ h0w) {
  int gid = blockIdx.x * blockDim.x + threadIdx.x;
  int n = blockDim.x * gridDim.x;
  for (int i = gid; i < B_ * U_; i += n) h0w[i] = 0u;  // h_0 = 0, tag 0
}

// X[t][b][e] = (fp16) emb[sentence[b][t]][e]; one thread = 8 elements.
__global__ void prep_x_kernel(const int* __restrict__ sent,
                              const float* __restrict__ emb,
                              _Float16* __restrict__ X) {
  int gid = blockIdx.x * blockDim.x + threadIdx.x;  // 2,097,152 total
  int e8 = gid & 31;
  int row = gid >> 5;         // row = t*128 + b
  int b = row & 127;
  int t = row >> 7;
  int word = sent[b * T_ + t];
  const float* src = emb + (size_t)word * E_ + e8 * 8;
  float4 v0 = *(const float4*)(src);
  float4 v1 = *(const float4*)(src + 4);
  _Float16 o0[8] = {(_Float16)v0.x, (_Float16)v0.y, (_Float16)v0.z, (_Float16)v0.w,
                    (_Float16)v1.x, (_Float16)v1.y, (_Float16)v1.z, (_Float16)v1.w};
  _Float16* dst = X + (size_t)row * E_ + e8 * 8;
  *(half8*)dst = *(half8*)o0;
}

__global__ __launch_bounds__(512, 1) void lstm_kernel(
    const _Float16* __restrict__ X,
    const float* __restrict__ Wx, const float* __restrict__ Wh,
    const float* __restrict__ bias,
    u32t* __restrict__ H0, u32t* __restrict__ H1) {
  // LDS: Hs [32 rows][HROW_] fp16 (33,280 B) | Rs float[2][4][2][256][4]
  // (65,536 B) = 98,816 B.
  __shared__ __align__(16) char smem[98816];
  _Float16* Hs = (_Float16*)smem;
  float* Rs = (float*)(smem + 33280);

  const int g = blockIdx.x;
  const int q = g >> 5;   // batch quarter: rows q*32 .. q*32+31
  const int s = g & 31;   // unit slice: units s*16 .. s*16+15
  const int tid = threadIdx.x;
  const int lane = tid & 63;
  const int wave = tid >> 6;      // 8 waves
  const int p16 = lane & 15;
  const int quad = lane >> 4;
  const int sg = wave & 1;        // unit subgroup (8 units)
  const int kq = wave >> 1;       // K quarter: K32 blocks kq*6 .. kq*6+5

  const bool lo = (p16 < 8);
  const int uo = p16 & 7;
  const int gu = s * 16 + sg * 8 + uo;               // global unit id
  const float bias0 = bias[(lo ? 0 : 512) + gu];     // i or f
  const float bias1 = bias[(lo ? 1024 : 1536) + gu]; // g or o

  // ---- one-time: gather B-fragments into registers ----
  // tile0 = [i|f] cols, tile1 = [g|o] cols. B-frag (16x16x32 f16):
  // lane holds B[k = quad*8 + j][n = p16], 8 contiguous k.
  const int C0 = ((p16 >> 3) & 1) * 512 + s * 16 + sg * 8 + (p16 & 7);  // i/f
  const int C1 = C0 + 1024;                                             // g/o
  half8 b0r[6], b1r[6];
#pragma unroll
  for (int i = 0; i < 6; ++i) {
    int kb = kq * 6 + i;
#pragma unroll
    for (int j = 0; j < 8; ++j) {
      int gk = kb * 32 + quad * 8 + j;
      float w0, w1;
      if (gk < E_) {
        w0 = Wx[(size_t)gk * 2048 + C0];
        w1 = Wx[(size_t)gk * 2048 + C1];
      } else {
        w0 = Wh[(size_t)(gk - E_) * 2048 + C0];
        w1 = Wh[(size_t)(gk - E_) * 2048 + C1];
      }
      b0r[i][j] = (_Float16)w0;
      b1r[i][j] = (_Float16)w1;
    }
  }

  float cst[4] = {0.f, 0.f, 0.f, 0.f};  // c-state (epilogue waves, lo lanes)

  // A-frag batch rows (mt = 0: rows 0-15, mt = 1: rows 16-31 of quarter)
  const int br0 = q * 32 + 0 * 16 + p16;
  const int br1 = q * 32 + 1 * 16 + p16;
  const int ka = quad * 8;   // A k-offset within a K32 block

  // epilogue slot (waves 0-3): slot = wv*64 + lane, wv = mt*2 + sg
  const int eslot = wave * 64 + lane;
  // writer slots: (mt*2 + sg)*64 + quad*16 + p16
  const int wslot0 = (0 * 2 + sg) * 64 + quad * 16 + p16;
  const int wslot1 = (1 * 2 + sg) * 64 + quad * 16 + p16;

  const u64t TM = 0xffff0000ffff0000ULL;

  for (int t = 0; t < T_; ++t) {
    const int pin = t & 1;
    const u32t* __restrict__ Hin = pin ? H1 : H0;
    u32t* __restrict__ Hout = pin ? H0 : H1;

    floatx4 a00 = {0.f, 0.f, 0.f, 0.f};  // mt0 x tile0
    floatx4 a01 = {0.f, 0.f, 0.f, 0.f};  // mt0 x tile1
    floatx4 a10 = {0.f, 0.f, 0.f, 0.f};  // mt1 x tile0
    floatx4 a11 = {0.f, 0.f, 0.f, 0.f};  // mt1 x tile1

    // ---- phase A: x-blocks (kb < 8), no h dependency ----
    const _Float16* xb = X + ((size_t)t * B_) * E_;
#pragma unroll
    for (int i = 0; i < 6; ++i) {
      int kb = kq * 6 + i;
      if (kb < 8) {
        half8 a0 = *(const half8*)(xb + (size_t)br0 * E_ + kb * 32 + ka);
        half8 a1 = *(const half8*)(xb + (size_t)br1 * E_ + kb * 32 + ka);
        a00 = __builtin_amdgcn_mfma_f32_16x16x32_f16(a0, b0r[i], a00, 0, 0, 0);
        a01 = __builtin_amdgcn_mfma_f32_16x16x32_f16(a0, b1r[i], a01, 0, 0, 0);
        a10 = __builtin_amdgcn_mfma_f32_16x16x32_f16(a1, b0r[i], a10, 0, 0, 0);
        a11 = __builtin_amdgcn_mfma_f32_16x16x32_f16(a1, b1r[i], a11, 0, 0, 0);
      }
    }

    // ---- phase B: detect + stage h_t (R4-proven coalesced retry loop) ----
    // chunk ci = wave*16+j: row r = ci>>2, seg = ci&3 (128 units each);
    // lane covers units seg*128 + lane*2, +1  (contiguous u64 -> 512B/instr).
    u64t hv[16];
    u32t done = 0;
    const u32t tgt = (u32t)t;
    for (;;) {
#pragma unroll
      for (int j = 0; j < 16; ++j) {
        if (!((done >> j) & 1)) {
          int ci = wave * 16 + j;
          int r = ci >> 2, seg = ci & 3;
          const u64t* src =
              (const u64t*)(Hin + (size_t)(q * 32 + r) * U_ + seg * 128) + lane;
          hv[j] = __hip_atomic_load(src, __ATOMIC_RELAXED,
                                    __HIP_MEMORY_SCOPE_AGENT);
        }
      }
      u32t nd = done;
#pragma unroll
      for (int j = 0; j < 16; ++j) {
        if (!((nd >> j) & 1)) {
          u32t lo32 = (u32t)hv[j];
          u32t hi32 = (u32t)(hv[j] >> 32);
          if (((lo32 >> 16) == tgt) & ((hi32 >> 16) == tgt)) nd |= (1u << j);
        }
      }
      done = nd;
      if (__all(done == 0xffffu)) break;
      __builtin_amdgcn_s_sleep(1);
    }
#pragma unroll
    for (int j = 0; j < 16; ++j) {
      int ci = wave * 16 + j;
      int r = ci >> 2, seg = ci & 3;
      u32t packed = ((u32t)hv[j] & 0xffffu) |
                    ((u32t)(hv[j] >> 16) & 0xffff0000u);
      *(u32t*)(Hs + r * HROW_ + seg * 128 + lane * 2) = packed;
    }
    __syncthreads();  // B2: slab ready

    // ---- phase C: h-blocks (kb >= 8) from slab, b128 A-frags ----
#pragma unroll
    for (int i = 0; i < 6; ++i) {
      int kb = kq * 6 + i;
      if (kb >= 8) {
        int hk = (kb - 8) * 32 + ka;
        half8 a0 = *(const half8*)(Hs + (0 * 16 + p16) * HROW_ + hk);
        half8 a1 = *(const half8*)(Hs + (1 * 16 + p16) * HROW_ + hk);
        a00 = __builtin_amdgcn_mfma_f32_16x16x32_f16(a0, b0r[i], a00, 0, 0, 0);
        a01 = __builtin_amdgcn_mfma_f32_16x16x32_f16(a0, b1r[i], a01, 0, 0, 0);
        a10 = __builtin_amdgcn_mfma_f32_16x16x32_f16(a1, b0r[i], a10, 0, 0, 0);
        a11 = __builtin_amdgcn_mfma_f32_16x16x32_f16(a1, b1r[i], a11, 0, 0, 0);
      }
    }

    // ---- write partials (all 8 waves): floatx4 slots ----
    {
      float* wb = Rs + (size_t)((pin * 4 + kq) * 2) * 1024;
      *(floatx4*)(wb + wslot0 * 4) = a00;
      *(floatx4*)(wb + 1024 + wslot0 * 4) = a01;
      *(floatx4*)(wb + wslot1 * 4) = a10;
      *(floatx4*)(wb + 1024 + wslot1 * 4) = a11;
    }
    __syncthreads();  // B3: partials ready

    // ---- epilogue (waves 0-3): reduce 4 kq, gates, tagged publish ----
    if (wave < 4) {
      floatx4 z0v = {0.f, 0.f, 0.f, 0.f};
      floatx4 z1v = {0.f, 0.f, 0.f, 0.f};
#pragma unroll
      for (int k2 = 0; k2 < 4; ++k2) {
        const float* rb = Rs + (size_t)((pin * 4 + k2) * 2) * 1024;
        z0v += *(const floatx4*)(rb + eslot * 4);
        z1v += *(const floatx4*)(rb + 1024 + eslot * 4);
      }
      const int mt = wave >> 1;  // eslot wv = mt*2 + sg, sg = wave&1 (matches)
#pragma unroll
      for (int r = 0; r < 4; ++r) {
        float z0 = z0v[r] + bias0;  // i (lo) / f (hi)
        float z1 = z1v[r] + bias1;  // g (lo) / o (hi)
        float s0 = sigmf(z0);
        float s1 = lo ? tanh_f(z1) : sigmf(z1);
        float prod = s0 * s1;                          // i*g on lo lanes
        float fg = __shfl_xor(lo ? prod : s0, 8, 64);  // lo receives f
        float og = __shfl_xor(s1, 8, 64);              // lo receives o
        if (lo) {
          float cn = fg * cst[r] + prod;
          cst[r] = cn;
          float h = og * tanh_f(cn);
          int row = q * 32 + mt * 16 + quad * 4 + r;
          _Float16 hf16 = (_Float16)h;
          u32t hb = ((u32t)(t + 1) << 16) |
                    (u32t)__builtin_bit_cast(unsigned short, hf16);
          __hip_atomic_store(&Hout[(size_t)row * U_ + gu], hb,
                             __ATOMIC_RELAXED, __HIP_MEMORY_SCOPE_AGENT);
        }
      }
    }
    // no end barrier: consumers gate on per-value tags.
  }
}

// MLP head: one block per batch row. h(512)->relu 128->relu 64->sigmoid 1.
// T=512 even -> final h in H0 (tagged u32).
__global__ void head_kernel(const u32t* __restrict__ H0,
                            const float* __restrict__ W1, const float* __restrict__ b1,
                            const float* __restrict__ W2, const float* __restrict__ b2,
                            const float* __restrict__ W3, const float* __restrict__ b3,
                            float* __restrict__ out) {
  __shared__ float hs[512];
  __shared__ float h1[128];
  __shared__ float h2[64];
  int row = blockIdx.x;
  int tid = threadIdx.x;  // 128 threads
  for (int k = tid; k < 512; k += 128) {
    unsigned short hb = (unsigned short)(H0[(size_t)row * U_ + k] & 0xffffu);
    hs[k] = (float)__builtin_bit_cast(_Float16, hb);
  }
  __syncthreads();
  float a = b1[tid];
  for (int k = 0; k < 512; ++k) a += hs[k] * W1[k * 128 + tid];
  h1[tid] = fmaxf(a, 0.0f);
  __syncthreads();
  if (tid < 64) {
    float a2 = b2[tid];
    for (int k = 0; k < 128; ++k) a2 += h1[k] * W2[k * 64 + tid];
    h2[tid] = fmaxf(a2, 0.0f);
  }
  __syncthreads();
  if (tid == 0) {
    float a3 = b3[0];
    for (int k = 0; k < 64; ++k) a3 += h2[k] * W3[k];
    out[row] = 1.0f / (1.0f + __expf(-a3));
  }
}

extern "C" void kernel_launch(void* const* d_in, const int* in_sizes, int n_in,
                              void* d_out, int out_size, void* d_ws, size_t ws_size,
                              hipStream_t stream) {
  const int* sent = (const int*)d_in[0];
  const float* emb = (const float*)d_in[1];
  const float* Wx = (const float*)d_in[2];
  const float* Wh = (const float*)d_in[3];
  const float* b = (const float*)d_in[4];
  const float* W1 = (const float*)d_in[5];
  const float* b1 = (const float*)d_in[6];
  const float* W2 = (const float*)d_in[7];
  const float* b2 = (const float*)d_in[8];
  const float* W3 = (const float*)d_in[9];
  const float* b3 = (const float*)d_in[10];
  float* out = (float*)d_out;

  char* ws = (char*)d_ws;
  _Float16* X = (_Float16*)(ws);
  u32t* H0 = (u32t*)(ws + (size_t)33554432);
  u32t* H1 = (u32t*)(ws + (size_t)33554432 + 262144);

  init_ws_kernel<<<64, 256, 0, stream>>>(H0);
  prep_x_kernel<<<8192, 256, 0, stream>>>(sent, emb, X);
  lstm_kernel<<<NWG_, 512, 0, stream>>>(X, Wx, Wh, b, H0, H1);
  head_kernel<<<128, 128, 0, stream>>>(H0, W1, b1, W2, b2, W3, b3, out);
}

// Round 9
// 2866.883 us; speedup vs baseline: 1.6327x; 1.1465x over previous
//
#include <hip/hip_runtime.h>
#include <hip/hip_bf16.h>
#include <hip/hip_fp16.h>

// LSTM_RNN: B=128, T=512, E=256, U=512. R9: R4 skeleton + ordered-flag
// handshake with 2-line poll + pure-fp16 bulk exchange.
//   - 128 wgs = 4 batch-quarters x 32 unit-slices (16 units / 64 gate cols).
//     Proven-co-resident grid; only R1-R6-proven constructs (agent atomics,
//     syncthreads, sleep-poll). No inline asm / s_getreg / sc0 (R7/R8 hung).
//   - Publish: epilogue stores fp16 h (agent u16 stores) -> B4 syncthreads
//     (drains vmcnt(0) for all waves, m97) -> tid0 stores ONE flag u32 = t+1.
//   - Consume: poll quarter's 32 flags (128 B = 2 cache lines, all waves
//     independently) until all == t; then bulk-read 32 KB fp16 ONCE
//     (coalesced u64 agent loads, 512 B/instr), LDS slab, h-GEMM. Address
//     of bulk loads carries a dependency on the final flag value (always
//     +0, opaque) so they cannot be hoisted above the poll.
//   - vs R4: half the exchange volume (fp16 not tag+fp16), no tag-strip
//     VALU, retry rounds cost 2 lines not 1024. 3 barriers/step (B2,B3,B4).
//   - No H/flag init: t=0 skips consumption (h0=0); flag poison 0xAAAAAAAA
//     never equals t in [1,512]. WAR: 2-step parity induction (R4) + B4.
// ws layout (~33.8 MiB):
//   X     fp16 [T][B][E]        @ 0          (33,554,432 B)
//   Hq    fp16 [2][4][32][512]  @ 33,554,432 (262,144 B)
//   flags u32  [2][4][32]       @ 33,816,576 (1,024 B)

#define B_ 128
#define T_ 512
#define E_ 256
#define U_ 512
#define NWG_ 128
#define KP_ 772     // Wl row stride (halves)
#define HROW_ 520   // H-slab row stride (halves)

typedef __attribute__((ext_vector_type(4))) _Float16 half4;
typedef __attribute__((ext_vector_type(4))) float floatx4;
typedef unsigned long long u64t;
typedef unsigned int u32t;

#define MFMA16 __builtin_amdgcn_mfma_f32_16x16x16f16

__device__ __forceinline__ float sigmf(float x) { return 1.0f / (1.0f + __expf(-x)); }
__device__ __forceinline__ float tanh_f(float x) { return 2.0f / (1.0f + __expf(-2.0f * x)) - 1.0f; }

// X[t][b][e] = (fp16) emb[sentence[b][t]][e]; one thread = 8 elements.
__global__ void prep_x_kernel(const int* __restrict__ sent,
                              const float* __restrict__ emb,
                              _Float16* __restrict__ X) {
  int gid = blockIdx.x * blockDim.x + threadIdx.x;  // 2,097,152 total
  int e8 = gid & 31;
  int row = gid >> 5;         // row = t*128 + b
  int b = row & 127;
  int t = row >> 7;
  int word = sent[b * T_ + t];
  const float* src = emb + (size_t)word * E_ + e8 * 8;
  float4 v0 = *(const float4*)(src);
  float4 v1 = *(const float4*)(src + 4);
  _Float16 o[8] = {(_Float16)v0.x, (_Float16)v0.y, (_Float16)v0.z, (_Float16)v0.w,
                   (_Float16)v1.x, (_Float16)v1.y, (_Float16)v1.z, (_Float16)v1.w};
  _Float16* dst = X + (size_t)row * E_ + e8 * 8;
  *(half4*)dst = *(half4*)o;
  *(half4*)(dst + 4) = *(half4*)(o + 4);
}

__global__ __launch_bounds__(512, 1) void lstm_kernel(
    const _Float16* __restrict__ X,
    const float* __restrict__ Wx, const float* __restrict__ Wh,
    const float* __restrict__ bias,
    _Float16* __restrict__ Hq, u32t* __restrict__ flags) {
  // LDS: Wl [64][KP_] fp16 (98,816) | Hs [32][HROW_] fp16 (33,280) |
  //      Rs float[8][256] (8,192) = 140,288 B (R4-equal).
  __shared__ __align__(16) char smem[140288];
  _Float16* Wl = (_Float16*)smem;
  _Float16* Hs = (_Float16*)(smem + 98816);
  float* Rs = (float*)(smem + 132096);

  const int g = blockIdx.x;
  const int q = g >> 5;   // batch quarter: rows q*32 .. q*32+31
  const int s = g & 31;   // unit slice: units s*16 .. s*16+15
  const int tid = threadIdx.x;
  const int lane = tid & 63;
  const int wave = tid >> 6;      // 8 waves
  const int p16 = lane & 15;
  const int quad = lane >> 4;
  const int sg = wave & 1;        // unit subgroup (8 units)
  const int mt = (wave >> 1) & 1; // M-tile (16 batch rows)
  const int kh = wave >> 2;       // 0: h[256,512)+epilogue; 1: x + h[0,256)

  // ---- one-time: stage weight slice [768 x 64] into LDS (R4-verbatim) ----
  for (int idx = tid; idx < 64 * 768; idx += 512) {
    int c = idx & 63, k = idx >> 6;
    int cc = c & 31;
    int gi = ((cc >> 3) & 1) + ((cc >> 4) << 1);       // 0=i,1=f,2=g,3=o
    int C = gi * 512 + s * 16 + (c >> 5) * 8 + (cc & 7);
    float w = (k < E_) ? Wx[(size_t)k * 2048 + C] : Wh[(size_t)(k - E_) * 2048 + C];
    Wl[c * KP_ + k] = (_Float16)w;
  }
  __syncthreads();

  const bool lo = (p16 < 8);
  const int uo = p16 & 7;
  const int gu = s * 16 + sg * 8 + uo;               // global unit id
  const float bias0 = bias[(lo ? 0 : 512) + gu];     // i or f
  const float bias1 = bias[(lo ? 1024 : 1536) + gu]; // g or o

  float cst[4] = {0.f, 0.f, 0.f, 0.f};  // c-state (kh0 waves, lo lanes)

  const int brow = q * 32 + mt * 16 + p16;  // A-frag batch row
  const int ko = quad * 4;

  const _Float16* bp0 = &Wl[(sg * 32 + p16) * KP_ + ko];       // [i|f] col
  const _Float16* bp1 = &Wl[(sg * 32 + 16 + p16) * KP_ + ko];  // [g|o] col

  for (int t = 0; t < T_; ++t) {
    const int pin = t & 1, pout = pin ^ 1;

    floatx4 acc0 = {0.f, 0.f, 0.f, 0.f};
    floatx4 acc1 = {0.f, 0.f, 0.f, 0.f};

    // ---- x-part on kh1 (overlaps kh0's previous-step epilogue) ----
    if (kh == 1) {
      const _Float16* xr = X + ((size_t)t * B_ + brow) * E_ + ko;
#pragma unroll
      for (int kk = 0; kk < 16; ++kk) {
        half4 a = *(const half4*)(xr + kk * 16);
        half4 b0 = *(const half4*)(bp0 + kk * 16);
        half4 b1 = *(const half4*)(bp1 + kk * 16);
        acc0 = MFMA16(a, b0, acc0, 0, 0, 0);
        acc1 = MFMA16(a, b1, acc1, 0, 0, 0);
      }
    }

    if (t > 0) {
      // ---- detect: poll quarter's 32 flags (2 cache lines) ----
      const u32t* fl = flags + (size_t)(pin * 4 + q) * 32;
      u32t vlast;
      for (;;) {
        vlast = __hip_atomic_load(fl + (lane & 31), __ATOMIC_RELAXED,
                                  __HIP_MEMORY_SCOPE_AGENT);
        if (__all(vlast == (u32t)t)) break;
        __builtin_amdgcn_s_sleep(1);
      }
      // opaque zero offset: pins bulk loads after the poll (addr dependency)
      const size_t dep = (size_t)(vlast >> 16);  // t < 65536 -> always 0

      // ---- transfer: bulk-read quarter slab ONCE (32 KB fp16) ----
      // wave w: rows 4w..4w+3; chunk j: row 4w+(j>>1), half j&1 (256 units);
      // lane -> units half*256 + lane*4.. +3 (contiguous u64, 512B/instr).
      const _Float16* hq = Hq + ((size_t)(pin * 4 + q) * 32) * 512 + dep;
      u64t hv[8];
#pragma unroll
      for (int j = 0; j < 8; ++j) {
        int row = wave * 4 + (j >> 1), half = j & 1;
        hv[j] = __hip_atomic_load(
            (const u64t*)(hq + (size_t)row * 512 + half * 256) + lane,
            __ATOMIC_RELAXED, __HIP_MEMORY_SCOPE_AGENT);
      }
#pragma unroll
      for (int j = 0; j < 8; ++j) {
        int row = wave * 4 + (j >> 1), half = j & 1;
        *(u64t*)(Hs + row * HROW_ + half * 256 + lane * 4) = hv[j];
      }
    }
    __syncthreads();  // B2: slab ready (uniform: all waves, every t)

    if (t > 0) {
      // ---- h-part from slab: kh0 -> cols [256,512), kh1 -> [0,256) ----
      const _Float16* ar = Hs + (mt * 16 + p16) * HROW_ + ko;
      const int hbase = kh ? 0 : 16;
#pragma unroll
      for (int kk = 0; kk < 16; ++kk) {
        int hk = hbase + kk;
        half4 a = *(const half4*)(ar + hk * 16);
        half4 b0 = *(const half4*)(bp0 + 256 + hk * 16);
        half4 b1 = *(const half4*)(bp1 + 256 + hk * 16);
        acc0 = MFMA16(a, b0, acc0, 0, 0, 0);
        acc1 = MFMA16(a, b1, acc1, 0, 0, 0);
      }
    }

    // ---- kh1 partials -> Rs ----
    if (kh == 1) {
      int base = (wave - 4) * 64 + lane;
#pragma unroll
      for (int r = 0; r < 4; ++r) {
        Rs[r * 256 + base] = acc0[r];
        Rs[(4 + r) * 256 + base] = acc1[r];
      }
    }
    __syncthreads();  // B3: partials ready (B2(t+1) fences next overwrite)

    // ---- epilogue (kh0): reduce, gates, fp16 publish ----
    if (kh == 0) {
      int base = wave * 64 + lane;
#pragma unroll
      for (int r = 0; r < 4; ++r) {
        float z0 = acc0[r] + Rs[r * 256 + base] + bias0;       // i (lo)/ f (hi)
        float z1 = acc1[r] + Rs[(4 + r) * 256 + base] + bias1; // g (lo)/ o (hi)
        float s0 = sigmf(z0);
        float s1 = lo ? tanh_f(z1) : sigmf(z1);
        float prod = s0 * s1;                          // i*g on lo lanes
        float fg = __shfl_xor(lo ? prod : s0, 8, 64);  // lo receives f
        float og = __shfl_xor(s1, 8, 64);              // lo receives o
        if (lo) {
          float cn = fg * cst[r] + prod;
          cst[r] = cn;
          float h = og * tanh_f(cn);
          int rowl = mt * 16 + quad * 4 + r;           // local row in quarter
          _Float16 hf16 = (_Float16)h;
          unsigned short hb = __builtin_bit_cast(unsigned short, hf16);
          __hip_atomic_store(
              (unsigned short*)(Hq + ((size_t)(pout * 4 + q) * 32 + rowl) * 512 + gu),
              hb, __ATOMIC_RELAXED, __HIP_MEMORY_SCOPE_AGENT);
        }
      }
    }

    // ---- B4: drains vmcnt(0) for ALL waves (h stores at LLC) -> flag ----
    __syncthreads();
    if (tid == 0)
      __hip_atomic_store(&flags[(size_t)(pout * 4 + q) * 32 + s], (u32t)(t + 1),
                         __ATOMIC_RELAXED, __HIP_MEMORY_SCOPE_AGENT);
  }
}

// MLP head: one block per batch row. h(512)->relu 128->relu 64->sigmoid 1.
// T=512 even -> final h in Hq parity 0. Kernel boundary orders prior stores.
__global__ void head_kernel(const _Float16* __restrict__ Hq,
                            const float* __restrict__ W1, const float* __restrict__ b1,
                            const float* __restrict__ W2, const float* __restrict__ b2,
                            const float* __restrict__ W3, const float* __restrict__ b3,
                            float* __restrict__ out) {
  __shared__ float hs[512];
  __shared__ float h1[128];
  __shared__ float h2[64];
  int row = blockIdx.x;
  int tid = threadIdx.x;  // 128 threads
  int q = row >> 5, rowl = row & 31;
  const _Float16* hrow = Hq + ((size_t)q * 32 + rowl) * 512;
  for (int k = tid; k < 512; k += 128) hs[k] = (float)hrow[k];
  __syncthreads();
  float a = b1[tid];
  for (int k = 0; k < 512; ++k) a += hs[k] * W1[k * 128 + tid];
  h1[tid] = fmaxf(a, 0.0f);
  __syncthreads();
  if (tid < 64) {
    float a2 = b2[tid];
    for (int k = 0; k < 128; ++k) a2 += h1[k] * W2[k * 64 + tid];
    h2[tid] = fmaxf(a2, 0.0f);
  }
  __syncthreads();
  if (tid == 0) {
    float a3 = b3[0];
    for (int k = 0; k < 64; ++k) a3 += h2[k] * W3[k];
    out[row] = 1.0f / (1.0f + __expf(-a3));
  }
}

extern "C" void kernel_launch(void* const* d_in, const int* in_sizes, int n_in,
                              void* d_out, int out_size, void* d_ws, size_t ws_size,
                              hipStream_t stream) {
  const int* sent = (const int*)d_in[0];
  const float* emb = (const float*)d_in[1];
  const float* Wx = (const float*)d_in[2];
  const float* Wh = (const float*)d_in[3];
  const float* b = (const float*)d_in[4];
  const float* W1 = (const float*)d_in[5];
  const float* b1 = (const float*)d_in[6];
  const float* W2 = (const float*)d_in[7];
  const float* b2 = (const float*)d_in[8];
  const float* W3 = (const float*)d_in[9];
  const float* b3 = (const float*)d_in[10];
  float* out = (float*)d_out;

  char* ws = (char*)d_ws;
  _Float16* X = (_Float16*)(ws);
  _Float16* Hq = (_Float16*)(ws + (size_t)33554432);
  u32t* flags = (u32t*)(ws + (size_t)33554432 + 262144);

  prep_x_kernel<<<8192, 256, 0, stream>>>(sent, emb, X);
  lstm_kernel<<<NWG_, 512, 0, stream>>>(X, Wx, Wh, b, Hq, flags);
  head_kernel<<<128, 128, 0, stream>>>(Hq, W1, b1, W2, b2, W3, b3, out);
}